// Round 8
// baseline (1306.156 us; speedup 1.0000x reference)
//
#include <hip/hip_runtime.h>

// ---------------------------------------------------------------------------
// GCN forward, fp16 datapath, SLICE-MAJOR feature layout.
//   Feature tensors stored as [8 slices][N][16 ch] fp16 so that the edge
//   gather can be XCD-partitioned: block (slice=blockIdx&7, chunk) touches
//   only a 3.2MB slice of H -> L2-resident per XCD.
//   per layer: H = dinv[r]*(A @ W)   (f16 MFMA, W hi/lo split, slice-major io)
//              A'[d] = relu(dinv[d]*(sum_{s in N(d)} H[s] + H[d]) + b)
//   pool: mean over sorted batch ids, then 128->10 head.
// Output: y[512*10] ++ global_mean[512*128], fp32.
// ---------------------------------------------------------------------------

#define ATOMIC_ADD_F32(p, v) __hip_atomic_fetch_add((p), (v), __ATOMIC_RELAXED, __HIP_MEMORY_SCOPE_AGENT)

constexpr int NG = 512;   // NUM_GRAPHS
constexpr float LO_SCALE = 4096.f;      // 2^12
constexpr float LO_INV   = 1.f / 4096.f;

typedef _Float16 half8 __attribute__((ext_vector_type(8)));
typedef float f32x4 __attribute__((ext_vector_type(4)));

// --- degree (XCD-partitioned histogram; deg = in-edge count) -----------------
__global__ __launch_bounds__(256) void k_deg_count_xcd(const int* __restrict__ dst,
                                                       int* __restrict__ deg,
                                                       int E, int N) {
    const int range = blockIdx.x & 7;
    const int chunk = blockIdx.x >> 3;
    const int nchunks = gridDim.x >> 3;
    const int csz = (E + nchunks - 1) / nchunks;
    const int lo = chunk * csz;
    const int hi = min(lo + csz, E);
    const int nr = N / 8;
    const int rlo = range * nr;
    const int rhi = (range == 7) ? N : rlo + nr;
    for (int i = lo + threadIdx.x; i < hi; i += 256) {
        int d = dst[i];
        if (d >= rlo && d < rhi) atomicAdd(&deg[d], 1);
    }
}

// --- exclusive scan of deg -> rowptr; dinv = rsqrt(deg+1) --------------------
__global__ __launch_bounds__(256) void k_scan_local(const int* __restrict__ deg,
                                                    int* __restrict__ rowptr,
                                                    int* __restrict__ partials,
                                                    float* __restrict__ dinv, int N) {
    __shared__ int s[256];
    int t = threadIdx.x;
    int i = blockIdx.x * 256 + t;
    int dg = (i < N) ? deg[i] : 0;
    if (i < N) dinv[i] = rsqrtf((float)(dg + 1));
    s[t] = dg;
    __syncthreads();
#pragma unroll
    for (int off = 1; off < 256; off <<= 1) {
        int add = (t >= off) ? s[t - off] : 0;
        __syncthreads();
        s[t] += add;
        __syncthreads();
    }
    if (i < N) rowptr[i] = s[t] - dg;
    if (t == 255) partials[blockIdx.x] = s[t];
}

__global__ __launch_bounds__(512) void k_scan_partials(int* __restrict__ partials, int nblk) {
    __shared__ int s[512];
    int t = threadIdx.x;
    int v = (t < nblk) ? partials[t] : 0;
    s[t] = v;
    __syncthreads();
#pragma unroll
    for (int off = 1; off < 512; off <<= 1) {
        int add = (t >= off) ? s[t - off] : 0;
        __syncthreads();
        s[t] += add;
        __syncthreads();
    }
    if (t < nblk) partials[t] = s[t] - v;
}

// also seeds cursor = rowptr
__global__ __launch_bounds__(256) void k_scan_apply(const int* __restrict__ deg,
                                                    int* __restrict__ rowptr,
                                                    int* __restrict__ cursor,
                                                    const int* __restrict__ partials, int N) {
    int i = blockIdx.x * 256 + threadIdx.x;
    if (i < N) {
        int r = rowptr[i] + partials[blockIdx.x];
        rowptr[i] = r;
        cursor[i] = r;
        if (i == N - 1) rowptr[N] = r + deg[i];
    }
}

// --- CSR fill, XCD-partitioned ------------------------------------------------
__global__ __launch_bounds__(256) void k_csr_fill_xcd(const int* __restrict__ src,
                                                      const int* __restrict__ dst,
                                                      int* __restrict__ cursor,
                                                      int* __restrict__ csr_src,
                                                      int E, int N) {
    const int range = blockIdx.x & 7;
    const int chunk = blockIdx.x >> 3;
    const int nchunks = gridDim.x >> 3;
    const int csz = (E + nchunks - 1) / nchunks;
    const int lo = chunk * csz;
    const int hi = min(lo + csz, E);
    const int nr = N / 8;
    const int rlo = range * nr;
    const int rhi = (range == 7) ? N : rlo + nr;
    for (int i = lo + threadIdx.x; i < hi; i += 256) {
        int d = dst[i];
        if (d >= rlo && d < rhi) {
            int pos = atomicAdd(&cursor[d], 1);
            csr_src[pos] = src[i];
        }
    }
}

// --- W prep: all 4 layers in one launch ----------------------------------------
struct WSplitArgs {
    const float* W[4];
    _Float16* Wth[4];
    _Float16* Wtl[4];
};
__global__ __launch_bounds__(256) void k_wsplit4(WSplitArgs a) {
    int idx = blockIdx.x * 256 + threadIdx.x;   // 4 * 16384 total
    int layer = idx >> 14;
    int e = idx & 16383;
    int k = e >> 7, c = e & 127;
    float w = a.W[layer][e];
    _Float16 hi = (_Float16)w;
    float lo = (w - (float)hi) * LO_SCALE;
    a.Wth[layer][c * 128 + k] = hi;
    a.Wtl[layer][c * 128 + k] = (_Float16)lo;
}

// --- X prep: fp32 row-major -> fp16 slice-major --------------------------------
// thread handles 4 channels (one float4): slice = gg>>2, u32 offset (gg&3)*2
__global__ __launch_bounds__(256) void k_xslice(const float* __restrict__ X,
                                                _Float16* __restrict__ P, int N) {
    int i = blockIdx.x * 256 + threadIdx.x;     // over N*32 float4 groups
    if (i >= N * 32) return;
    int n = i >> 5, gg = i & 31;
    float4 v = ((const float4*)X)[i];
    union { uint2 u2; _Float16 h[4]; } o;
    o.h[0] = (_Float16)v.x; o.h[1] = (_Float16)v.y;
    o.h[2] = (_Float16)v.z; o.h[3] = (_Float16)v.w;
    unsigned* Pu = (unsigned*)P;
    size_t base = (size_t)(gg >> 2) * ((size_t)N * 8) + (size_t)n * 8 + (gg & 3) * 2;
    *(uint2*)(Pu + base) = o.u2;
}

// --- GEMM: H = dinv[r]*(A @ W), f16 MFMA, slice-major A and H ------------------
__global__ __launch_bounds__(256) void k_gemm_f16(const _Float16* __restrict__ A,
                                                  const _Float16* __restrict__ Wth,
                                                  const _Float16* __restrict__ Wtl,
                                                  const float* __restrict__ dinv,
                                                  _Float16* __restrict__ H, int N) {
    const size_t SLS = (size_t)N * 16;          // fp16 per slice
    const int tid = threadIdx.x;
    const int wave = tid >> 6;
    const int l = tid & 63;
    const int wrow = wave & 1;
    const int wcol = wave >> 1;
    const int lr = l & 15;
    const int q = l >> 4;                       // 0..3

    const int row_base = blockIdx.x * 64 + wrow * 32;
    const int c_base = wcol * 64;

    f32x4 acch[2][4], accl[2][4];
#pragma unroll
    for (int rt = 0; rt < 2; ++rt)
#pragma unroll
        for (int ct = 0; ct < 4; ++ct) {
            acch[rt][ct] = (f32x4){0.f, 0.f, 0.f, 0.f};
            accl[rt][ct] = (f32x4){0.f, 0.f, 0.f, 0.f};
        }

#pragma unroll
    for (int ks = 0; ks < 4; ++ks) {
        const int koff = ks * 32 + q * 8;

        half8 bh[4], bl[4];
#pragma unroll
        for (int ct = 0; ct < 4; ++ct) {
            size_t off = (size_t)(c_base + ct * 16 + lr) * 128 + koff;
            bh[ct] = *(const half8*)(Wth + off);
            bl[ct] = *(const half8*)(Wtl + off);
        }

        // A slice-major: slice = koff>>4, within-slice offset = koff&15
        const _Float16* Asl = A + (size_t)(koff >> 4) * SLS + (koff & 15);
        half8 a[2];
#pragma unroll
        for (int rt = 0; rt < 2; ++rt) {
            int r = row_base + rt * 16 + lr;
            if (r >= N) r = N - 1;                 // clamp; stores guarded
            a[rt] = *(const half8*)(Asl + (size_t)r * 16);
        }

#pragma unroll
        for (int rt = 0; rt < 2; ++rt)
#pragma unroll
            for (int ct = 0; ct < 4; ++ct) {
                acch[rt][ct] = __builtin_amdgcn_mfma_f32_16x16x32_f16(a[rt], bh[ct], acch[rt][ct], 0, 0, 0);
                accl[rt][ct] = __builtin_amdgcn_mfma_f32_16x16x32_f16(a[rt], bl[ct], accl[rt][ct], 0, 0, 0);
            }
    }

    // store: D frag col = lane&15, row = q*4 + j ; scale by dinv[row]
#pragma unroll
    for (int rt = 0; rt < 2; ++rt) {
        int r0 = row_base + rt * 16 + q * 4;
        float dv[4];
#pragma unroll
        for (int j = 0; j < 4; ++j) dv[j] = (r0 + j < N) ? dinv[r0 + j] : 0.f;
#pragma unroll
        for (int ct = 0; ct < 4; ++ct) {
            int col = c_base + ct * 16 + lr;
            _Float16* Hsl = H + (size_t)(col >> 4) * SLS + (col & 15);
#pragma unroll
            for (int j = 0; j < 4; ++j) {
                int r = r0 + j;
                if (r < N) {
                    float v = fmaf(accl[rt][ct][j], LO_INV, acch[rt][ct][j]);
                    Hsl[(size_t)r * 16] = (_Float16)(v * dv[j]);
                }
            }
        }
    }
}

// --- aggregate, slice-major + XCD-partitioned ----------------------------------
// block = (slice = blockIdx&7, chunk = blockIdx>>3); 4 waves x 32 dsts.
// lane: g = l>>3 edge-group, b = l&7 u32 position within the 32B slice row.
// 8 edges per load instruction; combine groups with shfl_xor 8/16/32.
__global__ __launch_bounds__(256) void k_agg_slice(const int* __restrict__ csr_src,
                                                   const int* __restrict__ rowptr,
                                                   const float* __restrict__ dinv,
                                                   const _Float16* __restrict__ H,
                                                   const float* __restrict__ bias,
                                                   _Float16* __restrict__ Aout, int N) {
    const int slice = blockIdx.x & 7;
    const int chunk = blockIdx.x >> 3;
    const int wave = threadIdx.x >> 6;
    const int l = threadIdx.x & 63;
    const int g = l >> 3;
    const int b = l & 7;
    const size_t SL8 = (size_t)N * 8;           // u32 per slice
    const unsigned* Hu = (const unsigned*)H + (size_t)slice * SL8;
    unsigned* Au = (unsigned*)Aout + (size_t)slice * SL8;

    union PK { unsigned u; _Float16 h[2]; };

    int d0 = chunk * 128 + wave * 32;
    int dend = min(d0 + 32, N);
    for (int d = d0; d < dend; ++d) {
        int beg = rowptr[d], end = rowptr[d + 1];
        float ax = 0.f, ay = 0.f;
        for (int j = beg; j < end; j += 16) {
            int e0 = j + g, e1 = j + 8 + g;
            if (e0 < end) {
                PK v; v.u = Hu[(size_t)csr_src[e0] * 8 + b];
                ax += (float)v.h[0]; ay += (float)v.h[1];
            }
            if (e1 < end) {
                PK v; v.u = Hu[(size_t)csr_src[e1] * 8 + b];
                ax += (float)v.h[0]; ay += (float)v.h[1];
            }
        }
        ax += __shfl_xor(ax, 8);  ay += __shfl_xor(ay, 8);
        ax += __shfl_xor(ax, 16); ay += __shfl_xor(ay, 16);
        ax += __shfl_xor(ax, 32); ay += __shfl_xor(ay, 32);
        if (l < 8) {
            PK s; s.u = Hu[(size_t)d * 8 + l];
            ax += (float)s.h[0]; ay += (float)s.h[1];
            float dd = dinv[d];
            float2 b2 = ((const float2*)bias)[slice * 8 + l];
            ax = fmaxf(fmaf(dd, ax, b2.x), 0.f);
            ay = fmaxf(fmaf(dd, ay, b2.y), 0.f);
            PK o; o.h[0] = (_Float16)ax; o.h[1] = (_Float16)ay;
            Au[(size_t)d * 8 + l] = o.u;
        }
    }
}

// --- pool: pooled[g] += A[i] (slice-major in), batch sorted --------------------
__global__ __launch_bounds__(128) void k_pool(const _Float16* __restrict__ A,
                                              const int* __restrict__ batch,
                                              float* __restrict__ pooled,
                                              float* __restrict__ counts, int N) {
    int t = threadIdx.x;
    const size_t SLS = (size_t)N * 16;
    const _Float16* base = A + (size_t)(t >> 4) * SLS + (t & 15);
    int i0 = blockIdx.x * 64;
    if (i0 >= N) return;
    int iend = min(i0 + 64, N);
    float acc = 0.f;
    int cnt = 0;
    int cur = batch[i0];
    for (int i = i0; i < iend; ++i) {
        int g = batch[i];
        if (g != cur) {
            ATOMIC_ADD_F32(&pooled[cur * 128 + t], acc);
            if (t == 0) ATOMIC_ADD_F32(&counts[cur], (float)cnt);
            acc = 0.f; cnt = 0; cur = g;
        }
        acc += (float)base[(size_t)i * 16];
        cnt++;
    }
    ATOMIC_ADD_F32(&pooled[cur * 128 + t], acc);
    if (t == 0) ATOMIC_ADD_F32(&counts[cur], (float)cnt);
}

// --- finalize: global_mean + head ------------------------------------------------
__global__ __launch_bounds__(128) void k_finalize(const float* __restrict__ pooled,
                                                  const float* __restrict__ counts,
                                                  const float* __restrict__ Wl,
                                                  const float* __restrict__ bl,
                                                  float* __restrict__ out) {
    int g = blockIdx.x;
    int t = threadIdx.x;
    __shared__ float m[128];
    float c = fmaxf(counts[g], 1.f);
    float mean = pooled[g * 128 + t] / c;
    out[NG * 10 + g * 128 + t] = mean;
    m[t] = mean;
    __syncthreads();
    if (t < 10) {
        float acc = bl[t];
#pragma unroll 16
        for (int k = 0; k < 128; ++k) acc = fmaf(m[k], Wl[k * 10 + t], acc);
        out[g * 10 + t] = acc;
    }
}

// ---------------------------------------------------------------------------
extern "C" void kernel_launch(void* const* d_in, const int* in_sizes, int n_in,
                              void* d_out, int out_size, void* d_ws, size_t ws_size,
                              hipStream_t stream) {
    const float* x     = (const float*)d_in[0];
    const int*   ei    = (const int*)d_in[1];
    const int*   batch = (const int*)d_in[2];
    const float* Wt[4] = { (const float*)d_in[3], (const float*)d_in[5],
                           (const float*)d_in[7], (const float*)d_in[9] };
    const float* bt[4] = { (const float*)d_in[4], (const float*)d_in[6],
                           (const float*)d_in[8], (const float*)d_in[10] };
    const float* Wl = (const float*)d_in[11];
    const float* bl = (const float*)d_in[12];
    float* out = (float*)d_out;

    const int N = in_sizes[0] / 128;
    const int E = in_sizes[1] / 2;
    const int* src = ei;
    const int* dst = ei + E;

    // workspace layout
    char* p = (char*)d_ws;
    _Float16* Pa    = (_Float16*)p;  p += (size_t)N * 128 * 2;
    _Float16* Pb    = (_Float16*)p;  p += (size_t)N * 128 * 2;
    _Float16* Hs    = (_Float16*)p;  p += (size_t)N * 128 * 2;
    float* dinv     = (float*)p;     p += (size_t)N * 4;
    int*   deg      = (int*)p;       p += (size_t)N * 4;
    int*   rowptr   = (int*)p;       p += (size_t)(N + 1) * 4;
    int*   cursor   = (int*)p;       p += (size_t)N * 4;
    int*   csr_src  = (int*)p;       p += (size_t)E * 4;
    int*   partials = (int*)p;       p += 512 * 4;
    float* pooled   = (float*)p;     p += (size_t)NG * 128 * 4;
    float* counts   = (float*)p;     p += (size_t)NG * 4;
    _Float16* Wsp   = (_Float16*)p;  p += 4 * 2 * 128 * 128 * 2;

    const int nblk = (N + 255) / 256;

    // degrees (edge count only; self-loop folded into dinv = rsqrt(deg+1))
    hipMemsetAsync(deg, 0, (size_t)N * 4, stream);
    k_deg_count_xcd<<<2048, 256, 0, stream>>>(dst, deg, E, N);

    // CSR build (by dst); scan fused with dinv + cursor seed
    k_scan_local<<<nblk, 256, 0, stream>>>(deg, rowptr, partials, dinv, N);
    k_scan_partials<<<1, 512, 0, stream>>>(partials, nblk);
    k_scan_apply<<<nblk, 256, 0, stream>>>(deg, rowptr, cursor, partials, N);
    k_csr_fill_xcd<<<2048, 256, 0, stream>>>(src, dst, cursor, csr_src, E, N);

    // weight splits (one launch) + X cast to slice-major
    WSplitArgs wa;
    _Float16* Wth[4]; _Float16* Wtl[4];
    for (int l = 0; l < 4; ++l) {
        Wth[l] = Wsp + (size_t)l * 2 * 16384;
        Wtl[l] = Wth[l] + 16384;
        wa.W[l] = Wt[l];
        wa.Wth[l] = Wth[l];
        wa.Wtl[l] = Wtl[l];
    }
    k_wsplit4<<<256, 256, 0, stream>>>(wa);
    k_xslice<<<(N * 32 + 255) / 256, 256, 0, stream>>>(x, Pa, N);

    // layers (split kernels; slice-major feature tensors)
    const int gemm_blocks = (N + 63) / 64;
    const int agg_blocks = 8 * ((N + 127) / 128);
    _Float16* pin = Pa;
    _Float16* pout = Pb;
    for (int l = 0; l < 4; ++l) {
        k_gemm_f16<<<gemm_blocks, 256, 0, stream>>>(pin, Wth[l], Wtl[l], dinv, Hs, N);
        k_agg_slice<<<agg_blocks, 256, 0, stream>>>(csr_src, rowptr, dinv, Hs, bt[l], pout, N);
        _Float16* tmp = pin; pin = pout; pout = tmp;
    }
    // final activations in pin

    // pool + head
    hipMemsetAsync(pooled, 0, (size_t)(NG * 128 + NG) * 4, stream);
    k_pool<<<(N + 63) / 64, 128, 0, stream>>>(pin, batch, pooled, counts, N);
    k_finalize<<<NG, 128, 0, stream>>>(pooled, counts, Wl, bl, out);
}

// Round 9
// 716.041 us; speedup vs baseline: 1.8241x; 1.8241x over previous
//
#include <hip/hip_runtime.h>

// ---------------------------------------------------------------------------
// GCN forward, fp16 datapath + XCD-partitioned CSR build. (round-6 structure)
//   prep:  deg/dinv, CSR(dst)->src (XCD-local scatter), W -> fp16 hi/lo.
//   layer: H' = dinv[r] * (A @ W)        (f16 MFMA, 2 products, split acc)
//          A_next[d] = relu( dinv[d]*(sum_{s in N(d)} H'[s] + H'[d]) + b )
//   layer 0 GEMM reads fp32 X directly (in-register fp16 convert).
//   pool:  mean over sorted batch ids (fp16 in), then 128->10 head.
// Output: y[512*10] ++ global_mean[512*128], fp32.
// ---------------------------------------------------------------------------

#define ATOMIC_ADD_F32(p, v) __hip_atomic_fetch_add((p), (v), __ATOMIC_RELAXED, __HIP_MEMORY_SCOPE_AGENT)

constexpr int NG = 512;   // NUM_GRAPHS
constexpr float LO_SCALE = 4096.f;      // 2^12
constexpr float LO_INV   = 1.f / 4096.f;

typedef _Float16 half8 __attribute__((ext_vector_type(8)));
typedef float f32x4 __attribute__((ext_vector_type(4)));

// --- degree (XCD-partitioned histogram; deg = in-edge count) -----------------
__global__ __launch_bounds__(256) void k_deg_count_xcd(const int* __restrict__ dst,
                                                       int* __restrict__ deg,
                                                       int E, int N) {
    const int range = blockIdx.x & 7;
    const int chunk = blockIdx.x >> 3;
    const int nchunks = gridDim.x >> 3;
    const int csz = (E + nchunks - 1) / nchunks;
    const int lo = chunk * csz;
    const int hi = min(lo + csz, E);
    const int nr = N / 8;
    const int rlo = range * nr;
    const int rhi = (range == 7) ? N : rlo + nr;
    for (int i = lo + threadIdx.x; i < hi; i += 256) {
        int d = dst[i];
        if (d >= rlo && d < rhi) atomicAdd(&deg[d], 1);
    }
}

// --- exclusive scan of deg -> rowptr; dinv = rsqrt(deg+1) --------------------
__global__ __launch_bounds__(256) void k_scan_local(const int* __restrict__ deg,
                                                    int* __restrict__ rowptr,
                                                    int* __restrict__ partials,
                                                    float* __restrict__ dinv, int N) {
    __shared__ int s[256];
    int t = threadIdx.x;
    int i = blockIdx.x * 256 + t;
    int dg = (i < N) ? deg[i] : 0;
    if (i < N) dinv[i] = rsqrtf((float)(dg + 1));
    s[t] = dg;
    __syncthreads();
#pragma unroll
    for (int off = 1; off < 256; off <<= 1) {
        int add = (t >= off) ? s[t - off] : 0;
        __syncthreads();
        s[t] += add;
        __syncthreads();
    }
    if (i < N) rowptr[i] = s[t] - dg;
    if (t == 255) partials[blockIdx.x] = s[t];
}

__global__ __launch_bounds__(512) void k_scan_partials(int* __restrict__ partials, int nblk) {
    __shared__ int s[512];
    int t = threadIdx.x;
    int v = (t < nblk) ? partials[t] : 0;
    s[t] = v;
    __syncthreads();
#pragma unroll
    for (int off = 1; off < 512; off <<= 1) {
        int add = (t >= off) ? s[t - off] : 0;
        __syncthreads();
        s[t] += add;
        __syncthreads();
    }
    if (t < nblk) partials[t] = s[t] - v;
}

// also seeds cursor = rowptr
__global__ __launch_bounds__(256) void k_scan_apply(const int* __restrict__ deg,
                                                    int* __restrict__ rowptr,
                                                    int* __restrict__ cursor,
                                                    const int* __restrict__ partials, int N) {
    int i = blockIdx.x * 256 + threadIdx.x;
    if (i < N) {
        int r = rowptr[i] + partials[blockIdx.x];
        rowptr[i] = r;
        cursor[i] = r;
        if (i == N - 1) rowptr[N] = r + deg[i];
    }
}

// --- CSR fill, XCD-partitioned ------------------------------------------------
__global__ __launch_bounds__(256) void k_csr_fill_xcd(const int* __restrict__ src,
                                                      const int* __restrict__ dst,
                                                      int* __restrict__ cursor,
                                                      int* __restrict__ csr_src,
                                                      int E, int N) {
    const int range = blockIdx.x & 7;
    const int chunk = blockIdx.x >> 3;
    const int nchunks = gridDim.x >> 3;
    const int csz = (E + nchunks - 1) / nchunks;
    const int lo = chunk * csz;
    const int hi = min(lo + csz, E);
    const int nr = N / 8;
    const int rlo = range * nr;
    const int rhi = (range == 7) ? N : rlo + nr;
    for (int i = lo + threadIdx.x; i < hi; i += 256) {
        int d = dst[i];
        if (d >= rlo && d < rhi) {
            int pos = atomicAdd(&cursor[d], 1);
            csr_src[pos] = src[i];
        }
    }
}

// --- W prep: all 4 layers in one launch ----------------------------------------
struct WSplitArgs {
    const float* W[4];
    _Float16* Wth[4];
    _Float16* Wtl[4];
};
__global__ __launch_bounds__(256) void k_wsplit4(WSplitArgs a) {
    int idx = blockIdx.x * 256 + threadIdx.x;   // 4 * 16384 total
    int layer = idx >> 14;
    int e = idx & 16383;
    int k = e >> 7, c = e & 127;
    float w = a.W[layer][e];
    _Float16 hi = (_Float16)w;
    float lo = (w - (float)hi) * LO_SCALE;
    a.Wth[layer][c * 128 + k] = hi;
    a.Wtl[layer][c * 128 + k] = (_Float16)lo;
}

// --- GEMM: H' = dinv[r] * (A @ W), f16 MFMA, 2 products, split accumulator ---
// AFP32=1: A is fp32 (layer 0, reads X directly); else fp16.
template <int AFP32>
__global__ __launch_bounds__(256) void k_gemm_f16(const void* __restrict__ Aptr,
                                                  const _Float16* __restrict__ Wth,
                                                  const _Float16* __restrict__ Wtl,
                                                  const float* __restrict__ dinv,
                                                  _Float16* __restrict__ Hh, int N) {
    const int tid = threadIdx.x;
    const int wave = tid >> 6;
    const int l = tid & 63;
    const int wrow = wave & 1;
    const int wcol = wave >> 1;
    const int lr = l & 15;
    const int q = l >> 4;

    const int row_base = blockIdx.x * 64 + wrow * 32;
    const int c_base = wcol * 64;

    f32x4 acch[2][4], accl[2][4];
#pragma unroll
    for (int rt = 0; rt < 2; ++rt)
#pragma unroll
        for (int ct = 0; ct < 4; ++ct) {
            acch[rt][ct] = (f32x4){0.f, 0.f, 0.f, 0.f};
            accl[rt][ct] = (f32x4){0.f, 0.f, 0.f, 0.f};
        }

#pragma unroll
    for (int ks = 0; ks < 4; ++ks) {
        const int koff = ks * 32 + q * 8;

        half8 bh[4], bl[4];
#pragma unroll
        for (int ct = 0; ct < 4; ++ct) {
            size_t off = (size_t)(c_base + ct * 16 + lr) * 128 + koff;
            bh[ct] = *(const half8*)(Wth + off);
            bl[ct] = *(const half8*)(Wtl + off);
        }

        half8 a[2];
#pragma unroll
        for (int rt = 0; rt < 2; ++rt) {
            int r = row_base + rt * 16 + lr;
            if (r >= N) r = N - 1;                 // clamp; stores guarded
            if constexpr (AFP32) {
                const float* xp = (const float*)Aptr + (size_t)r * 128 + koff;
                float4 f0 = *(const float4*)xp;
                float4 f1 = *(const float4*)(xp + 4);
                half8 h;
                h[0] = (_Float16)f0.x; h[1] = (_Float16)f0.y;
                h[2] = (_Float16)f0.z; h[3] = (_Float16)f0.w;
                h[4] = (_Float16)f1.x; h[5] = (_Float16)f1.y;
                h[6] = (_Float16)f1.z; h[7] = (_Float16)f1.w;
                a[rt] = h;
            } else {
                a[rt] = *(const half8*)((const _Float16*)Aptr + (size_t)r * 128 + koff);
            }
        }

#pragma unroll
        for (int rt = 0; rt < 2; ++rt)
#pragma unroll
            for (int ct = 0; ct < 4; ++ct) {
                acch[rt][ct] = __builtin_amdgcn_mfma_f32_16x16x32_f16(a[rt], bh[ct], acch[rt][ct], 0, 0, 0);
                accl[rt][ct] = __builtin_amdgcn_mfma_f32_16x16x32_f16(a[rt], bl[ct], accl[rt][ct], 0, 0, 0);
            }
    }

    // store: D frag: col = lane&15, row = q*4 + j ; scale by dinv[row]
#pragma unroll
    for (int rt = 0; rt < 2; ++rt) {
        int r0 = row_base + rt * 16 + q * 4;
        float dv[4];
#pragma unroll
        for (int j = 0; j < 4; ++j) dv[j] = (r0 + j < N) ? dinv[r0 + j] : 0.f;
#pragma unroll
        for (int ct = 0; ct < 4; ++ct) {
            int col = c_base + ct * 16 + lr;
#pragma unroll
            for (int j = 0; j < 4; ++j) {
                int r = r0 + j;
                if (r < N) {
                    float v = fmaf(accl[rt][ct][j], LO_INV, acch[rt][ct][j]);
                    Hh[(size_t)r * 128 + col] = (_Float16)(v * dv[j]);
                }
            }
        }
    }
}

// --- aggregate (CSR gather, fp16 rows): one wave per dst node -----------------
// 16-deep edge batch; nontemporal index loads (csr_src is one-touch stream).
__global__ __launch_bounds__(256) void k_aggregate_f16(const int* __restrict__ csr_src,
                                                       const int* __restrict__ rowptr,
                                                       const float* __restrict__ dinv,
                                                       const _Float16* __restrict__ Hh,
                                                       const float* __restrict__ bias,
                                                       _Float16* __restrict__ Ah, int N) {
    int d = blockIdx.x * 4 + (threadIdx.x >> 6);
    if (d >= N) return;
    const int lane = threadIdx.x & 63;
    const unsigned* Hu = (const unsigned*)Hh;        // 64 dwords per row

    int beg = rowptr[d], end = rowptr[d + 1];
    union PK { unsigned u; _Float16 h[2]; };

    PK sv; sv.u = Hu[(size_t)d * 64 + lane];         // self term
    float ax = (float)sv.h[0];
    float ay = (float)sv.h[1];

    int j = beg;
    for (; j + 15 < end; j += 16) {
        int s[16]; PK v[16];
#pragma unroll
        for (int u = 0; u < 16; ++u) s[u] = __builtin_nontemporal_load(csr_src + j + u);
#pragma unroll
        for (int u = 0; u < 16; ++u) v[u].u = Hu[(size_t)s[u] * 64 + lane];
#pragma unroll
        for (int u = 0; u < 16; ++u) {
            ax += (float)v[u].h[0];
            ay += (float)v[u].h[1];
        }
    }
    for (; j + 7 < end; j += 8) {
        int s[8]; PK v[8];
#pragma unroll
        for (int u = 0; u < 8; ++u) s[u] = __builtin_nontemporal_load(csr_src + j + u);
#pragma unroll
        for (int u = 0; u < 8; ++u) v[u].u = Hu[(size_t)s[u] * 64 + lane];
#pragma unroll
        for (int u = 0; u < 8; ++u) {
            ax += (float)v[u].h[0];
            ay += (float)v[u].h[1];
        }
    }
    for (; j < end; ++j) {
        PK v; v.u = Hu[(size_t)__builtin_nontemporal_load(csr_src + j) * 64 + lane];
        ax += (float)v.h[0];
        ay += (float)v.h[1];
    }

    float dd = dinv[d];
    float2 b2 = ((const float2*)bias)[lane];
    ax = fmaxf(fmaf(dd, ax, b2.x), 0.f);
    ay = fmaxf(fmaf(dd, ay, b2.y), 0.f);

    PK o; o.h[0] = (_Float16)ax; o.h[1] = (_Float16)ay;
    ((unsigned*)Ah)[(size_t)d * 64 + lane] = o.u;
}

// --- pool: pooled[g] += A[i] (activations, bias+relu applied), batch sorted ----
__global__ __launch_bounds__(128) void k_pool(const _Float16* __restrict__ A,
                                              const int* __restrict__ batch,
                                              float* __restrict__ pooled,
                                              float* __restrict__ counts, int N) {
    int k = threadIdx.x;
    int i0 = blockIdx.x * 64;
    if (i0 >= N) return;
    int iend = min(i0 + 64, N);
    float acc = 0.f;
    int cnt = 0;
    int cur = batch[i0];
    for (int i = i0; i < iend; ++i) {
        int g = batch[i];
        if (g != cur) {
            ATOMIC_ADD_F32(&pooled[cur * 128 + k], acc);
            if (k == 0) ATOMIC_ADD_F32(&counts[cur], (float)cnt);
            acc = 0.f; cnt = 0; cur = g;
        }
        acc += (float)A[(size_t)i * 128 + k];
        cnt++;
    }
    ATOMIC_ADD_F32(&pooled[cur * 128 + k], acc);
    if (k == 0) ATOMIC_ADD_F32(&counts[cur], (float)cnt);
}

// --- finalize: global_mean + head ---------------------------------------------
__global__ __launch_bounds__(128) void k_finalize(const float* __restrict__ pooled,
                                                  const float* __restrict__ counts,
                                                  const float* __restrict__ Wl,
                                                  const float* __restrict__ bl,
                                                  float* __restrict__ out) {
    int g = blockIdx.x;
    int t = threadIdx.x;
    __shared__ float m[128];
    float c = fmaxf(counts[g], 1.f);
    float mean = pooled[g * 128 + t] / c;
    out[NG * 10 + g * 128 + t] = mean;
    m[t] = mean;
    __syncthreads();
    if (t < 10) {
        float acc = bl[t];
#pragma unroll 16
        for (int k = 0; k < 128; ++k) acc = fmaf(m[k], Wl[k * 10 + t], acc);
        out[g * 10 + t] = acc;
    }
}

// ---------------------------------------------------------------------------
extern "C" void kernel_launch(void* const* d_in, const int* in_sizes, int n_in,
                              void* d_out, int out_size, void* d_ws, size_t ws_size,
                              hipStream_t stream) {
    const float* x     = (const float*)d_in[0];
    const int*   ei    = (const int*)d_in[1];
    const int*   batch = (const int*)d_in[2];
    const float* Wt[4] = { (const float*)d_in[3], (const float*)d_in[5],
                           (const float*)d_in[7], (const float*)d_in[9] };
    const float* bt[4] = { (const float*)d_in[4], (const float*)d_in[6],
                           (const float*)d_in[8], (const float*)d_in[10] };
    const float* Wl = (const float*)d_in[11];
    const float* bl = (const float*)d_in[12];
    float* out = (float*)d_out;

    const int N = in_sizes[0] / 128;
    const int E = in_sizes[1] / 2;
    const int* src = ei;
    const int* dst = ei + E;

    // workspace layout
    char* p = (char*)d_ws;
    _Float16* Hh    = (_Float16*)p;  p += (size_t)N * 128 * 2;
    _Float16* Ah    = (_Float16*)p;  p += (size_t)N * 128 * 2;
    float* dinv     = (float*)p;     p += (size_t)N * 4;
    int*   deg      = (int*)p;       p += (size_t)N * 4;
    int*   rowptr   = (int*)p;       p += (size_t)(N + 1) * 4;
    int*   cursor   = (int*)p;       p += (size_t)N * 4;
    int*   csr_src  = (int*)p;       p += (size_t)E * 4;
    int*   partials = (int*)p;       p += 512 * 4;
    float* pooled   = (float*)p;     p += (size_t)NG * 128 * 4;
    float* counts   = (float*)p;     p += (size_t)NG * 4;
    _Float16* Wsp   = (_Float16*)p;  p += 4 * 2 * 128 * 128 * 2;

    const int nblk = (N + 255) / 256;

    // degrees (edge count only; self-loop folded into dinv = rsqrt(deg+1))
    hipMemsetAsync(deg, 0, (size_t)N * 4, stream);
    k_deg_count_xcd<<<2048, 256, 0, stream>>>(dst, deg, E, N);

    // CSR build (by dst); scan fused with dinv + cursor seed
    k_scan_local<<<nblk, 256, 0, stream>>>(deg, rowptr, partials, dinv, N);
    k_scan_partials<<<1, 512, 0, stream>>>(partials, nblk);
    k_scan_apply<<<nblk, 256, 0, stream>>>(deg, rowptr, cursor, partials, N);
    k_csr_fill_xcd<<<2048, 256, 0, stream>>>(src, dst, cursor, csr_src, E, N);

    // weight splits (one launch)
    WSplitArgs wa;
    _Float16* Wth[4]; _Float16* Wtl[4];
    for (int l = 0; l < 4; ++l) {
        Wth[l] = Wsp + (size_t)l * 2 * 16384;
        Wtl[l] = Wth[l] + 16384;
        wa.W[l] = Wt[l];
        wa.Wth[l] = Wth[l];
        wa.Wtl[l] = Wtl[l];
    }
    k_wsplit4<<<256, 256, 0, stream>>>(wa);

    // layers (layer 0 GEMM reads fp32 X directly)
    const int gemm_blocks = (N + 63) / 64;
    const int agg_blocks = (N + 3) / 4;
    k_gemm_f16<1><<<gemm_blocks, 256, 0, stream>>>(x, Wth[0], Wtl[0], dinv, Hh, N);
    k_aggregate_f16<<<agg_blocks, 256, 0, stream>>>(csr_src, rowptr, dinv, Hh, bt[0], Ah, N);
    for (int l = 1; l < 4; ++l) {
        k_gemm_f16<0><<<gemm_blocks, 256, 0, stream>>>(Ah, Wth[l], Wtl[l], dinv, Hh, N);
        k_aggregate_f16<<<agg_blocks, 256, 0, stream>>>(csr_src, rowptr, dinv, Hh, bt[l], Ah, N);
    }

    // pool + head
    hipMemsetAsync(pooled, 0, (size_t)(NG * 128 + NG) * 4, stream);
    k_pool<<<(N + 63) / 64, 128, 0, stream>>>(Ah, batch, pooled, counts, N);
    k_finalize<<<NG, 128, 0, stream>>>(pooled, counts, Wl, bl, out);
}

// Round 10
// 669.782 us; speedup vs baseline: 1.9501x; 1.0691x over previous
//
#include <hip/hip_runtime.h>

// ---------------------------------------------------------------------------
// GCN forward, fp16 datapath + XCD-partitioned CSR build. (round-6 structure,
// + layer-0 GEMM reads fp32 X directly; aggregate = round-6 exact form)
//   prep:  deg/dinv, CSR(dst)->src (XCD-local scatter), W -> fp16 hi/lo.
//   layer: H' = dinv[r] * (A @ W)        (f16 MFMA, 2 products, split acc)
//          A_next[d] = relu( dinv[d]*(sum_{s in N(d)} H'[s] + H'[d]) + b )
//   pool:  mean over sorted batch ids (fp16 in), then 128->10 head.
// Output: y[512*10] ++ global_mean[512*128], fp32.
// ---------------------------------------------------------------------------

#define ATOMIC_ADD_F32(p, v) __hip_atomic_fetch_add((p), (v), __ATOMIC_RELAXED, __HIP_MEMORY_SCOPE_AGENT)

constexpr int NG = 512;   // NUM_GRAPHS
constexpr float LO_SCALE = 4096.f;      // 2^12
constexpr float LO_INV   = 1.f / 4096.f;

typedef _Float16 half8 __attribute__((ext_vector_type(8)));
typedef float f32x4 __attribute__((ext_vector_type(4)));

// --- degree (XCD-partitioned histogram; deg = in-edge count) -----------------
__global__ __launch_bounds__(256) void k_deg_count_xcd(const int* __restrict__ dst,
                                                       int* __restrict__ deg,
                                                       int E, int N) {
    const int range = blockIdx.x & 7;
    const int chunk = blockIdx.x >> 3;
    const int nchunks = gridDim.x >> 3;
    const int csz = (E + nchunks - 1) / nchunks;
    const int lo = chunk * csz;
    const int hi = min(lo + csz, E);
    const int nr = N / 8;
    const int rlo = range * nr;
    const int rhi = (range == 7) ? N : rlo + nr;
    for (int i = lo + threadIdx.x; i < hi; i += 256) {
        int d = dst[i];
        if (d >= rlo && d < rhi) atomicAdd(&deg[d], 1);
    }
}

// --- exclusive scan of deg -> rowptr; dinv = rsqrt(deg+1) --------------------
__global__ __launch_bounds__(256) void k_scan_local(const int* __restrict__ deg,
                                                    int* __restrict__ rowptr,
                                                    int* __restrict__ partials,
                                                    float* __restrict__ dinv, int N) {
    __shared__ int s[256];
    int t = threadIdx.x;
    int i = blockIdx.x * 256 + t;
    int dg = (i < N) ? deg[i] : 0;
    if (i < N) dinv[i] = rsqrtf((float)(dg + 1));
    s[t] = dg;
    __syncthreads();
#pragma unroll
    for (int off = 1; off < 256; off <<= 1) {
        int add = (t >= off) ? s[t - off] : 0;
        __syncthreads();
        s[t] += add;
        __syncthreads();
    }
    if (i < N) rowptr[i] = s[t] - dg;
    if (t == 255) partials[blockIdx.x] = s[t];
}

__global__ __launch_bounds__(512) void k_scan_partials(int* __restrict__ partials, int nblk) {
    __shared__ int s[512];
    int t = threadIdx.x;
    int v = (t < nblk) ? partials[t] : 0;
    s[t] = v;
    __syncthreads();
#pragma unroll
    for (int off = 1; off < 512; off <<= 1) {
        int add = (t >= off) ? s[t - off] : 0;
        __syncthreads();
        s[t] += add;
        __syncthreads();
    }
    if (t < nblk) partials[t] = s[t] - v;
}

// also seeds cursor = rowptr
__global__ __launch_bounds__(256) void k_scan_apply(const int* __restrict__ deg,
                                                    int* __restrict__ rowptr,
                                                    int* __restrict__ cursor,
                                                    const int* __restrict__ partials, int N) {
    int i = blockIdx.x * 256 + threadIdx.x;
    if (i < N) {
        int r = rowptr[i] + partials[blockIdx.x];
        rowptr[i] = r;
        cursor[i] = r;
        if (i == N - 1) rowptr[N] = r + deg[i];
    }
}

// --- CSR fill, XCD-partitioned ------------------------------------------------
__global__ __launch_bounds__(256) void k_csr_fill_xcd(const int* __restrict__ src,
                                                      const int* __restrict__ dst,
                                                      int* __restrict__ cursor,
                                                      int* __restrict__ csr_src,
                                                      int E, int N) {
    const int range = blockIdx.x & 7;
    const int chunk = blockIdx.x >> 3;
    const int nchunks = gridDim.x >> 3;
    const int csz = (E + nchunks - 1) / nchunks;
    const int lo = chunk * csz;
    const int hi = min(lo + csz, E);
    const int nr = N / 8;
    const int rlo = range * nr;
    const int rhi = (range == 7) ? N : rlo + nr;
    for (int i = lo + threadIdx.x; i < hi; i += 256) {
        int d = dst[i];
        if (d >= rlo && d < rhi) {
            int pos = atomicAdd(&cursor[d], 1);
            csr_src[pos] = src[i];
        }
    }
}

// --- W prep: all 4 layers in one launch ----------------------------------------
struct WSplitArgs {
    const float* W[4];
    _Float16* Wth[4];
    _Float16* Wtl[4];
};
__global__ __launch_bounds__(256) void k_wsplit4(WSplitArgs a) {
    int idx = blockIdx.x * 256 + threadIdx.x;   // 4 * 16384 total
    int layer = idx >> 14;
    int e = idx & 16383;
    int k = e >> 7, c = e & 127;
    float w = a.W[layer][e];
    _Float16 hi = (_Float16)w;
    float lo = (w - (float)hi) * LO_SCALE;
    a.Wth[layer][c * 128 + k] = hi;
    a.Wtl[layer][c * 128 + k] = (_Float16)lo;
}

// --- GEMM: H' = dinv[r] * (A @ W), f16 MFMA, 2 products, split accumulator ---
// AFP32=1: A is fp32 (layer 0, reads X directly); else fp16.
template <int AFP32>
__global__ __launch_bounds__(256) void k_gemm_f16(const void* __restrict__ Aptr,
                                                  const _Float16* __restrict__ Wth,
                                                  const _Float16* __restrict__ Wtl,
                                                  const float* __restrict__ dinv,
                                                  _Float16* __restrict__ Hh, int N) {
    const int tid = threadIdx.x;
    const int wave = tid >> 6;
    const int l = tid & 63;
    const int wrow = wave & 1;
    const int wcol = wave >> 1;
    const int lr = l & 15;
    const int q = l >> 4;

    const int row_base = blockIdx.x * 64 + wrow * 32;
    const int c_base = wcol * 64;

    f32x4 acch[2][4], accl[2][4];
#pragma unroll
    for (int rt = 0; rt < 2; ++rt)
#pragma unroll
        for (int ct = 0; ct < 4; ++ct) {
            acch[rt][ct] = (f32x4){0.f, 0.f, 0.f, 0.f};
            accl[rt][ct] = (f32x4){0.f, 0.f, 0.f, 0.f};
        }

#pragma unroll
    for (int ks = 0; ks < 4; ++ks) {
        const int koff = ks * 32 + q * 8;

        half8 bh[4], bl[4];
#pragma unroll
        for (int ct = 0; ct < 4; ++ct) {
            size_t off = (size_t)(c_base + ct * 16 + lr) * 128 + koff;
            bh[ct] = *(const half8*)(Wth + off);
            bl[ct] = *(const half8*)(Wtl + off);
        }

        half8 a[2];
#pragma unroll
        for (int rt = 0; rt < 2; ++rt) {
            int r = row_base + rt * 16 + lr;
            if (r >= N) r = N - 1;                 // clamp; stores guarded
            if constexpr (AFP32) {
                const float* xp = (const float*)Aptr + (size_t)r * 128 + koff;
                float4 f0 = *(const float4*)xp;
                float4 f1 = *(const float4*)(xp + 4);
                half8 h;
                h[0] = (_Float16)f0.x; h[1] = (_Float16)f0.y;
                h[2] = (_Float16)f0.z; h[3] = (_Float16)f0.w;
                h[4] = (_Float16)f1.x; h[5] = (_Float16)f1.y;
                h[6] = (_Float16)f1.z; h[7] = (_Float16)f1.w;
                a[rt] = h;
            } else {
                a[rt] = *(const half8*)((const _Float16*)Aptr + (size_t)r * 128 + koff);
            }
        }

#pragma unroll
        for (int rt = 0; rt < 2; ++rt)
#pragma unroll
            for (int ct = 0; ct < 4; ++ct) {
                acch[rt][ct] = __builtin_amdgcn_mfma_f32_16x16x32_f16(a[rt], bh[ct], acch[rt][ct], 0, 0, 0);
                accl[rt][ct] = __builtin_amdgcn_mfma_f32_16x16x32_f16(a[rt], bl[ct], accl[rt][ct], 0, 0, 0);
            }
    }

    // store: D frag: col = lane&15, row = q*4 + j ; scale by dinv[row]
#pragma unroll
    for (int rt = 0; rt < 2; ++rt) {
        int r0 = row_base + rt * 16 + q * 4;
        float dv[4];
#pragma unroll
        for (int j = 0; j < 4; ++j) dv[j] = (r0 + j < N) ? dinv[r0 + j] : 0.f;
#pragma unroll
        for (int ct = 0; ct < 4; ++ct) {
            int col = c_base + ct * 16 + lr;
#pragma unroll
            for (int j = 0; j < 4; ++j) {
                int r = r0 + j;
                if (r < N) {
                    float v = fmaf(accl[rt][ct][j], LO_INV, acch[rt][ct][j]);
                    Hh[(size_t)r * 128 + col] = (_Float16)(v * dv[j]);
                }
            }
        }
    }
}

// --- aggregate (CSR gather, fp16 rows): one wave per dst node -----------------
// round-6 exact form: 8-deep unroll, plain cached loads (VGPR 20).
__global__ __launch_bounds__(256) void k_aggregate_f16(const int* __restrict__ csr_src,
                                                       const int* __restrict__ rowptr,
                                                       const float* __restrict__ dinv,
                                                       const _Float16* __restrict__ Hh,
                                                       const float* __restrict__ bias,
                                                       _Float16* __restrict__ Ah, int N) {
    int d = blockIdx.x * 4 + (threadIdx.x >> 6);
    if (d >= N) return;
    const int lane = threadIdx.x & 63;
    const unsigned* Hu = (const unsigned*)Hh;        // 64 dwords per row

    int beg = rowptr[d], end = rowptr[d + 1];
    union PK { unsigned u; _Float16 h[2]; };

    PK sv; sv.u = Hu[(size_t)d * 64 + lane];         // self term
    float ax = (float)sv.h[0];
    float ay = (float)sv.h[1];

    int j = beg;
    for (; j + 7 < end; j += 8) {
        int s[8]; PK v[8];
#pragma unroll
        for (int u = 0; u < 8; ++u) s[u] = csr_src[j + u];
#pragma unroll
        for (int u = 0; u < 8; ++u) v[u].u = Hu[(size_t)s[u] * 64 + lane];
#pragma unroll
        for (int u = 0; u < 8; ++u) {
            ax += (float)v[u].h[0];
            ay += (float)v[u].h[1];
        }
    }
    for (; j < end; ++j) {
        PK v; v.u = Hu[(size_t)csr_src[j] * 64 + lane];
        ax += (float)v.h[0];
        ay += (float)v.h[1];
    }

    float dd = dinv[d];
    float2 b2 = ((const float2*)bias)[lane];
    ax = fmaxf(fmaf(dd, ax, b2.x), 0.f);
    ay = fmaxf(fmaf(dd, ay, b2.y), 0.f);

    PK o; o.h[0] = (_Float16)ax; o.h[1] = (_Float16)ay;
    ((unsigned*)Ah)[(size_t)d * 64 + lane] = o.u;
}

// --- pool: pooled[g] += A[i] (activations, bias+relu applied), batch sorted ----
__global__ __launch_bounds__(128) void k_pool(const _Float16* __restrict__ A,
                                              const int* __restrict__ batch,
                                              float* __restrict__ pooled,
                                              float* __restrict__ counts, int N) {
    int k = threadIdx.x;
    int i0 = blockIdx.x * 64;
    if (i0 >= N) return;
    int iend = min(i0 + 64, N);
    float acc = 0.f;
    int cnt = 0;
    int cur = batch[i0];
    for (int i = i0; i < iend; ++i) {
        int g = batch[i];
        if (g != cur) {
            ATOMIC_ADD_F32(&pooled[cur * 128 + k], acc);
            if (k == 0) ATOMIC_ADD_F32(&counts[cur], (float)cnt);
            acc = 0.f; cnt = 0; cur = g;
        }
        acc += (float)A[(size_t)i * 128 + k];
        cnt++;
    }
    ATOMIC_ADD_F32(&pooled[cur * 128 + k], acc);
    if (k == 0) ATOMIC_ADD_F32(&counts[cur], (float)cnt);
}

// --- finalize: global_mean + head ---------------------------------------------
__global__ __launch_bounds__(128) void k_finalize(const float* __restrict__ pooled,
                                                  const float* __restrict__ counts,
                                                  const float* __restrict__ Wl,
                                                  const float* __restrict__ bl,
                                                  float* __restrict__ out) {
    int g = blockIdx.x;
    int t = threadIdx.x;
    __shared__ float m[128];
    float c = fmaxf(counts[g], 1.f);
    float mean = pooled[g * 128 + t] / c;
    out[NG * 10 + g * 128 + t] = mean;
    m[t] = mean;
    __syncthreads();
    if (t < 10) {
        float acc = bl[t];
#pragma unroll 16
        for (int k = 0; k < 128; ++k) acc = fmaf(m[k], Wl[k * 10 + t], acc);
        out[g * 10 + t] = acc;
    }
}

// ---------------------------------------------------------------------------
extern "C" void kernel_launch(void* const* d_in, const int* in_sizes, int n_in,
                              void* d_out, int out_size, void* d_ws, size_t ws_size,
                              hipStream_t stream) {
    const float* x     = (const float*)d_in[0];
    const int*   ei    = (const int*)d_in[1];
    const int*   batch = (const int*)d_in[2];
    const float* Wt[4] = { (const float*)d_in[3], (const float*)d_in[5],
                           (const float*)d_in[7], (const float*)d_in[9] };
    const float* bt[4] = { (const float*)d_in[4], (const float*)d_in[6],
                           (const float*)d_in[8], (const float*)d_in[10] };
    const float* Wl = (const float*)d_in[11];
    const float* bl = (const float*)d_in[12];
    float* out = (float*)d_out;

    const int N = in_sizes[0] / 128;
    const int E = in_sizes[1] / 2;
    const int* src = ei;
    const int* dst = ei + E;

    // workspace layout
    char* p = (char*)d_ws;
    _Float16* Hh    = (_Float16*)p;  p += (size_t)N * 128 * 2;
    _Float16* Ah    = (_Float16*)p;  p += (size_t)N * 128 * 2;
    float* dinv     = (float*)p;     p += (size_t)N * 4;
    int*   deg      = (int*)p;       p += (size_t)N * 4;
    int*   rowptr   = (int*)p;       p += (size_t)(N + 1) * 4;
    int*   cursor   = (int*)p;       p += (size_t)N * 4;
    int*   csr_src  = (int*)p;       p += (size_t)E * 4;
    int*   partials = (int*)p;       p += 512 * 4;
    float* pooled   = (float*)p;     p += (size_t)NG * 128 * 4;
    float* counts   = (float*)p;     p += (size_t)NG * 4;
    _Float16* Wsp   = (_Float16*)p;  p += 4 * 2 * 128 * 128 * 2;

    const int nblk = (N + 255) / 256;

    // degrees (edge count only; self-loop folded into dinv = rsqrt(deg+1))
    hipMemsetAsync(deg, 0, (size_t)N * 4, stream);
    k_deg_count_xcd<<<2048, 256, 0, stream>>>(dst, deg, E, N);

    // CSR build (by dst); scan fused with dinv + cursor seed
    k_scan_local<<<nblk, 256, 0, stream>>>(deg, rowptr, partials, dinv, N);
    k_scan_partials<<<1, 512, 0, stream>>>(partials, nblk);
    k_scan_apply<<<nblk, 256, 0, stream>>>(deg, rowptr, cursor, partials, N);
    k_csr_fill_xcd<<<2048, 256, 0, stream>>>(src, dst, cursor, csr_src, E, N);

    // weight splits (one launch)
    WSplitArgs wa;
    _Float16* Wth[4]; _Float16* Wtl[4];
    for (int l = 0; l < 4; ++l) {
        Wth[l] = Wsp + (size_t)l * 2 * 16384;
        Wtl[l] = Wth[l] + 16384;
        wa.W[l] = Wt[l];
        wa.Wth[l] = Wth[l];
        wa.Wtl[l] = Wtl[l];
    }
    k_wsplit4<<<256, 256, 0, stream>>>(wa);

    // layers (layer 0 GEMM reads fp32 X directly)
    const int gemm_blocks = (N + 63) / 64;
    const int agg_blocks = (N + 3) / 4;
    k_gemm_f16<1><<<gemm_blocks, 256, 0, stream>>>(x, Wth[0], Wtl[0], dinv, Hh, N);
    k_aggregate_f16<<<agg_blocks, 256, 0, stream>>>(csr_src, rowptr, dinv, Hh, bt[0], Ah, N);
    for (int l = 1; l < 4; ++l) {
        k_gemm_f16<0><<<gemm_blocks, 256, 0, stream>>>(Ah, Wth[l], Wtl[l], dinv, Hh, N);
        k_aggregate_f16<<<agg_blocks, 256, 0, stream>>>(csr_src, rowptr, dinv, Hh, bt[l], Ah, N);
    }

    // pool + head
    hipMemsetAsync(pooled, 0, (size_t)(NG * 128 + NG) * 4, stream);
    k_pool<<<(N + 63) / 64, 128, 0, stream>>>(Ah, batch, pooled, counts, N);
    k_finalize<<<NG, 128, 0, stream>>>(pooled, counts, Wl, bl, out);
}